// Round 10
// baseline (401.231 us; speedup 1.0000x reference)
//
#include <hip/hip_runtime.h>
#include <hip/hip_bf16.h>

// Dims (fixed by the reference)
#define B_   8
#define L_   512
#define DIN  128
#define DM   512
#define NLAY 2
#define DI   1024     // d_inner
#define DS   16       // d_state
#define DTR  32       // dt_rank
#define BL   (B_ * L_)   // 4096
#define KS   8           // x_proj split-K slices
#define CL   128         // scan chunk length (staged in LDS)
#define NCH  (L_ / CL)   // 4

typedef short bf16x8 __attribute__((ext_vector_type(8)));
typedef float floatx4 __attribute__((ext_vector_type(4)));

__device__ __forceinline__ unsigned short f2bf(float f) {
    unsigned int u = __float_as_uint(f);
    unsigned int r = (u + 0x7FFF + ((u >> 16) & 1)) >> 16;   // RNE
    return (unsigned short)r;
}
__device__ __forceinline__ float bf2f(unsigned short u) {
    return __uint_as_float((unsigned int)u << 16);
}

#if __has_builtin(__builtin_amdgcn_exp2f)
#define EXP2(x) __builtin_amdgcn_exp2f(x)
#else
#define EXP2(x) __expf((x) * 0.69314718056f)
#endif

// Async global->LDS, 16B per lane. LDS dest must be linear: wave-uniform base
// + lane*16 (m104/m108). Our chunk mapping satisfies this exactly.
__device__ __forceinline__ void gld_lds16(const unsigned short* g, unsigned short* l) {
    __builtin_amdgcn_global_load_lds(
        (const __attribute__((address_space(1))) void*)g,
        (__attribute__((address_space(3))) void*)l,
        16, 0, 0);
}

// Load 8 consecutive fp32 and pack to a bf16x8 fragment (RNE).
__device__ __forceinline__ bf16x8 ldcvt_bf8(const float* __restrict__ p) {
    float4 a = *(const float4*)p;
    float4 b = *(const float4*)(p + 4);
    unsigned short o[8];
    o[0] = f2bf(a.x); o[1] = f2bf(a.y); o[2] = f2bf(a.z); o[3] = f2bf(a.w);
    o[4] = f2bf(b.x); o[5] = f2bf(b.y); o[6] = f2bf(b.z); o[7] = f2bf(b.w);
    return *(bf16x8*)o;
}

// ---------------------------------------------------------------------------
// Fused fp32->bf16 conversion (x, proj_in_w, in_proj_w, out_proj_w, dt_proj_w
// stride-32 bf16) + zero hm + zero last-block counters.
// ---------------------------------------------------------------------------
__global__ __launch_bounds__(256) void cvt_all(
    const float* __restrict__ x,  unsigned short* __restrict__ xbf,
    const float* __restrict__ pw, unsigned short* __restrict__ wpin,
    const float* __restrict__ iw, unsigned short* __restrict__ win,
    const float* __restrict__ ow, unsigned short* __restrict__ wout,
    const float* __restrict__ dtp, unsigned short* __restrict__ dtwb,
    float* __restrict__ hm, int* __restrict__ cnt)
{
    int bid = blockIdx.x;
    if (bid >= 1856) {                       // zero hm (B_*DM = 4096 floats)
        if (bid == 1856 && threadIdx.x < 17)  // zero 68 ints of counters
            ((int4*)cnt)[threadIdx.x] = make_int4(0, 0, 0, 0);
        int i = (bid - 1856) * 2048 + threadIdx.x * 8;
        float4 z = make_float4(0.f, 0.f, 0.f, 0.f);
        *(float4*)(hm + i) = z;
        *(float4*)(hm + i + 4) = z;
        return;
    }
    const float* src; unsigned short* dst; int off;
    if      (bid < 256)  { src = x;   dst = xbf;  off = bid; }
    else if (bid < 288)  { src = pw;  dst = wpin; off = bid - 256; }
    else if (bid < 1312) { src = iw;  dst = win;  off = bid - 288; }
    else if (bid < 1824) { src = ow;  dst = wout; off = bid - 1312; }
    else                 { src = dtp; dst = dtwb; off = bid - 1824; }  // 32 blocks
    int i = (off * 256 + threadIdx.x) * 8;
    float4 a = *(const float4*)(src + i);
    float4 b = *(const float4*)(src + i + 4);
    unsigned short o[8];
    o[0] = f2bf(a.x); o[1] = f2bf(a.y); o[2] = f2bf(a.z); o[3] = f2bf(a.w);
    o[4] = f2bf(b.x); o[5] = f2bf(b.y); o[6] = f2bf(b.z); o[7] = f2bf(b.w);
    *(uint4*)(dst + i) = *(uint4*)o;
}

// ---------------------------------------------------------------------------
// bf16 MFMA GEMM, tile 128x128, BK=64, m97 structure (single-buffered):
// global_load_lds width-16 staging into linear LDS, 2 barriers per K-step.
// Used for in_proj (N=2048, K=512), grid 512.
// ---------------------------------------------------------------------------
__global__ __launch_bounds__(256) void gemm_mfma(
    const unsigned short* __restrict__ A,
    const unsigned short* __restrict__ W,
    float* __restrict__ C, unsigned short* __restrict__ Cb,
    int N, int K)
{
    __shared__ unsigned short As[128 * 64];   // 16 KB, linear (row stride 64 shorts)
    __shared__ unsigned short Ws[128 * 64];   // 16 KB

    const int tid  = threadIdx.x;
    const int lane = tid & 63;
    const int wv   = tid >> 6;
    const int wm   = (wv >> 1) * 64;
    const int wn   = (wv & 1) * 64;
    const int lr   = lane & 15;
    const int q    = lane >> 4;

    const int srow  = lane >> 3;          // row within chunk (0..7)
    const int skcol = (lane & 7) * 8;     // short col within row
    const long aRowBase = (long)blockIdx.y * 128;
    const long wRowBase = (long)blockIdx.x * 128;

    floatx4 acc[4][4];
#pragma unroll
    for (int i = 0; i < 4; ++i)
#pragma unroll
        for (int j = 0; j < 4; ++j)
#pragma unroll
            for (int r = 0; r < 4; ++r) acc[i][j][r] = 0.f;

    for (int k0 = 0; k0 < K; k0 += 64) {
        __syncthreads();
#pragma unroll
        for (int c = 0; c < 4; ++c) {
            const int chunk = wv * 4 + c;
            const int row   = chunk * 8 + srow;
            gld_lds16(A + (aRowBase + row) * K + k0 + skcol,
                      As + chunk * 512 + lane * 8);
            gld_lds16(W + (wRowBase + row) * K + k0 + skcol,
                      Ws + chunk * 512 + lane * 8);
        }
        __syncthreads();

#pragma unroll
        for (int kk = 0; kk < 2; ++kk) {
            bf16x8 af[4], bfr[4];
#pragma unroll
            for (int i = 0; i < 4; ++i)
                af[i] = *(const bf16x8*)(As + (wm + i * 16 + lr) * 64 + kk * 32 + q * 8);
#pragma unroll
            for (int j = 0; j < 4; ++j)
                bfr[j] = *(const bf16x8*)(Ws + (wn + j * 16 + lr) * 64 + kk * 32 + q * 8);
#pragma unroll
            for (int i = 0; i < 4; ++i)
#pragma unroll
                for (int j = 0; j < 4; ++j)
                    acc[i][j] = __builtin_amdgcn_mfma_f32_16x16x32_bf16(
                        af[i], bfr[j], acc[i][j], 0, 0, 0);
        }
    }

#pragma unroll
    for (int i = 0; i < 4; ++i) {
#pragma unroll
        for (int r = 0; r < 4; ++r) {
            const int  crow = blockIdx.y * 128 + wm + i * 16 + q * 4 + r;
            const long base = (long)crow * N + blockIdx.x * 128 + wn + lr;
#pragma unroll
            for (int j = 0; j < 4; ++j) {
                float v = acc[i][j][r];
                if (C)  C[base + j * 16] = v;
                if (Cb) Cb[base + j * 16] = f2bf(v);
            }
        }
    }
}

// ---------------------------------------------------------------------------
// bf16 MFMA GEMM, tile 128(M)x64(N), BK=64, m97-style staging (single-buffer).
// meanmode: accumulate column sums / L into hm; the LAST block (device-scope
// counter) then runs the classifier head in-block (saves a dispatch).
// ---------------------------------------------------------------------------
__global__ __launch_bounds__(256) void gemm_mfma_n64(
    const unsigned short* __restrict__ A,
    const unsigned short* __restrict__ W,
    const float* __restrict__ bias,
    float* __restrict__ C, unsigned short* __restrict__ Cb,
    int N, int K, int meanmode, float* __restrict__ hm,
    const float* __restrict__ w1, const float* __restrict__ b1,
    const float* __restrict__ w2, const float* __restrict__ b2,
    float* __restrict__ out, int* __restrict__ cnt2)
{
    __shared__ unsigned short As[128 * 64];   // 16 KB
    __shared__ unsigned short Ws[64 * 64];    // 8 KB
    __shared__ float colsum[64];
    __shared__ float clsbuf[DM + 64];
    __shared__ int lastFlag;

    const int tid  = threadIdx.x;
    const int lane = tid & 63;
    const int wv   = tid >> 6;
    const int wm   = wv * 32;
    const int lr   = lane & 15;
    const int q    = lane >> 4;

    const int srow  = lane >> 3;
    const int skcol = (lane & 7) * 8;
    const long aRowBase = (long)blockIdx.y * 128;
    const long wRowBase = (long)blockIdx.x * 64;

    floatx4 acc[2][4];
#pragma unroll
    for (int i = 0; i < 2; ++i)
#pragma unroll
        for (int j = 0; j < 4; ++j)
#pragma unroll
            for (int r = 0; r < 4; ++r) acc[i][j][r] = 0.f;

    for (int k0 = 0; k0 < K; k0 += 64) {
        __syncthreads();
#pragma unroll
        for (int c = 0; c < 4; ++c) {          // A: 16 chunks, 4 per wave
            const int chunk = wv * 4 + c;
            const int row   = chunk * 8 + srow;
            gld_lds16(A + (aRowBase + row) * K + k0 + skcol,
                      As + chunk * 512 + lane * 8);
        }
#pragma unroll
        for (int c = 0; c < 2; ++c) {          // W: 8 chunks, 2 per wave
            const int chunk = wv * 2 + c;
            const int row   = chunk * 8 + srow;
            gld_lds16(W + (wRowBase + row) * K + k0 + skcol,
                      Ws + chunk * 512 + lane * 8);
        }
        __syncthreads();

#pragma unroll
        for (int kk = 0; kk < 2; ++kk) {
            bf16x8 af[2], bfr[4];
#pragma unroll
            for (int i = 0; i < 2; ++i)
                af[i] = *(const bf16x8*)(As + (wm + i * 16 + lr) * 64 + kk * 32 + q * 8);
#pragma unroll
            for (int j = 0; j < 4; ++j)
                bfr[j] = *(const bf16x8*)(Ws + (j * 16 + lr) * 64 + kk * 32 + q * 8);
#pragma unroll
            for (int i = 0; i < 2; ++i)
#pragma unroll
                for (int j = 0; j < 4; ++j)
                    acc[i][j] = __builtin_amdgcn_mfma_f32_16x16x32_bf16(
                        af[i], bfr[j], acc[i][j], 0, 0, 0);
        }
    }

    if (meanmode) {
        if (tid < 64) colsum[tid] = 0.f;
        __syncthreads();
#pragma unroll
        for (int j = 0; j < 4; ++j) {
            float p = 0.f;
#pragma unroll
            for (int i = 0; i < 2; ++i)
#pragma unroll
                for (int r = 0; r < 4; ++r) p += acc[i][j][r];
            atomicAdd(&colsum[j * 16 + lr], p);
        }
        __syncthreads();
        if (tid < 64) {
            const int b = blockIdx.y >> 2;   // 4 row-blocks per batch
            atomicAdd(&hm[b * DM + blockIdx.x * 64 + tid],
                      colsum[tid] * (1.f / (float)L_));
        }
        __syncthreads();   // all hm atomics of this block drained
        if (tid == 0) {
            __threadfence();                          // release
            lastFlag = (atomicAdd(cnt2, 1) == 255);   // grid is 8x32 = 256
        }
        __syncthreads();
        if (lastFlag) {
            __threadfence();                          // acquire
            // classifier head, all 8 batches, 256 threads
            float* su = clsbuf + DM;
            for (int b = 0; b < B_; ++b) {
                clsbuf[tid]       = hm[b * DM + tid];
                clsbuf[tid + 256] = hm[b * DM + tid + 256];
                __syncthreads();
                const int jj = tid >> 2, sl = tid & 3;
                const float* wr = w1 + jj * DM + sl * 128;
                const float* hb = clsbuf + sl * 128;
                float p = 0.f;
                for (int k = 0; k < 128; k += 4)
                    p += hb[k] * wr[k] + hb[k+1] * wr[k+1]
                       + hb[k+2] * wr[k+2] + hb[k+3] * wr[k+3];
                p += __shfl_xor(p, 1);
                p += __shfl_xor(p, 2);
                if (sl == 0) su[jj] = fmaxf(p + b1[jj], 0.f) * w2[jj];
                __syncthreads();
                if (tid < 64) {
                    float v = su[tid];
#pragma unroll
                    for (int off = 32; off; off >>= 1) v += __shfl_down(v, off);
                    if (tid == 0) out[b] = v + b2[0];
                }
                __syncthreads();
            }
        }
        return;
    }

    float bj[4] = {0.f, 0.f, 0.f, 0.f};
    if (bias) {
#pragma unroll
        for (int j = 0; j < 4; ++j)
            bj[j] = bias[blockIdx.x * 64 + j * 16 + lr];
    }
#pragma unroll
    for (int i = 0; i < 2; ++i) {
#pragma unroll
        for (int r = 0; r < 4; ++r) {
            const int  crow = blockIdx.y * 128 + wm + i * 16 + q * 4 + r;
            const long base = (long)crow * N + blockIdx.x * 64 + lr;
#pragma unroll
            for (int j = 0; j < 4; ++j) {
                float v = acc[i][j][r] + bj[j];
                if (C)  C[base + j * 16] = v;
                if (Cb) Cb[base + j * 16] = f2bf(v);
            }
        }
    }
}

// ---------------------------------------------------------------------------
// Fused causal-conv(k=4)+silu + x_proj split-K stage 1 (partials to P).
// The LAST of the 8 slice-blocks per row-group (device-scope counter per by)
// reduces the partials into xdbl — folds the old xproj_reduce dispatch.
// xcout written d-chunked [DI/16][BL][16] (bit-exact layout).
// ---------------------------------------------------------------------------
__global__ __launch_bounds__(256) void xprojconv(
    const unsigned short* __restrict__ xzb, const float* __restrict__ cw,
    const float* __restrict__ cb, const float* __restrict__ W,
    float* __restrict__ P, float* __restrict__ xcout,
    float* __restrict__ xdbl, int* __restrict__ cnt)
{
    __shared__ float As[16][68];
    __shared__ float Ws[16][68];
    __shared__ int lastFlag;

    const int tid  = threadIdx.x;
    const int tx   = tid & 15;
    const int ty   = tid >> 4;
    const int lrow = tid >> 2;
    const int lk   = (tid & 3) << 2;
    const int kbase = blockIdx.x * (DI / KS);
    const int by   = blockIdx.y;

    const int m = by * 64 + lrow;
    const int t = m & (L_ - 1);
    const float* Wp = W + lrow * DI + kbase + lk;

    float acc[4][4] = {};

    for (int k0 = 0; k0 < DI / KS; k0 += 16) {
        const int dcol = kbase + k0 + lk;
        float4 cbv = *(const float4*)(cb + dcol);
        float sums[4] = {cbv.x, cbv.y, cbv.z, cbv.w};
        float4 cwq[4];
#pragma unroll
        for (int q = 0; q < 4; ++q) cwq[q] = *(const float4*)(cw + (dcol + q) * 4);
#pragma unroll
        for (int w = 0; w < 4; ++w) {
            int tw = t - 3 + w;
            if (tw >= 0) {
                const uint2 up = *(const uint2*)(xzb + (long)(m - 3 + w) * (2 * DI) + dcol);
                float x0 = __uint_as_float(up.x << 16);
                float x1 = __uint_as_float(up.x & 0xffff0000u);
                float x2 = __uint_as_float(up.y << 16);
                float x3 = __uint_as_float(up.y & 0xffff0000u);
                sums[0] += ((const float*)&cwq[0])[w] * x0;
                sums[1] += ((const float*)&cwq[1])[w] * x1;
                sums[2] += ((const float*)&cwq[2])[w] * x2;
                sums[3] += ((const float*)&cwq[3])[w] * x3;
            }
        }
        float4 a4;
#pragma unroll
        for (int q = 0; q < 4; ++q)
            ((float*)&a4)[q] = sums[q] / (1.f + __expf(-sums[q]));
        float4 wv = *(const float4*)(Wp + k0);
        *(float4*)(xcout + (long)(dcol >> 4) * (BL * 16) + (long)m * 16 + lk) = a4;

        __syncthreads();
        As[lk + 0][lrow] = a4.x; As[lk + 1][lrow] = a4.y;
        As[lk + 2][lrow] = a4.z; As[lk + 3][lrow] = a4.w;
        Ws[lk + 0][lrow] = wv.x; Ws[lk + 1][lrow] = wv.y;
        Ws[lk + 2][lrow] = wv.z; Ws[lk + 3][lrow] = wv.w;
        __syncthreads();
#pragma unroll
        for (int k = 0; k < 16; ++k) {
            const float4 a44 = *(const float4*)&As[k][ty << 2];
            const float4 w4  = *(const float4*)&Ws[k][tx << 2];
            acc[0][0] += a44.x * w4.x; acc[0][1] += a44.x * w4.y;
            acc[0][2] += a44.x * w4.z; acc[0][3] += a44.x * w4.w;
            acc[1][0] += a44.y * w4.x; acc[1][1] += a44.y * w4.y;
            acc[1][2] += a44.y * w4.z; acc[1][3] += a44.y * w4.w;
            acc[2][0] += a44.z * w4.x; acc[2][1] += a44.z * w4.y;
            acc[2][2] += a44.z * w4.z; acc[2][3] += a44.z * w4.w;
            acc[3][0] += a44.w * w4.x; acc[3][1] += a44.w * w4.y;
            acc[3][2] += a44.w * w4.z; acc[3][3] += a44.w * w4.w;
        }
    }

    float* outp = P + (long)blockIdx.x * (BL * 64)
                + (by * 64 + (ty << 2)) * 64 + (tx << 2);
#pragma unroll
    for (int i = 0; i < 4; ++i)
        *(float4*)(outp + i * 64) = make_float4(acc[i][0], acc[i][1],
                                                acc[i][2], acc[i][3]);

    // --- last-block split-K reduce for this row-group (no spinning) ---
    __syncthreads();   // all partial stores of this block drained
    if (tid == 0) {
        __threadfence();                            // release
        int old = atomicAdd(&cnt[by], 1);
        lastFlag = (old == KS - 1);
        if (old == KS - 1) atomicExch(&cnt[by], 0); // reset for next layer
    }
    __syncthreads();
    if (lastFlag) {
        __threadfence();                            // acquire
        const int base = by * 4096 + tid * 16;      // 64 rows x 64 cols
#pragma unroll
        for (int jj = 0; jj < 4; ++jj) {
            const int idx = base + jj * 4;
            float4 s = *(const float4*)(P + idx);
#pragma unroll
            for (int k = 1; k < KS; ++k) {
                float4 p = *(const float4*)(P + (long)k * (BL * 64) + idx);
                s.x += p.x; s.y += p.y; s.z += p.z; s.w += p.w;
            }
            *(float4*)(xdbl + idx) = s;
        }
    }
}

// ---------------------------------------------------------------------------
template <int CTRL>
__device__ __forceinline__ float dpp_shr_add(float v) {
    int sh = __builtin_amdgcn_update_dpp(0, __float_as_int(v), CTRL, 0xF, 0xF, true);
    return v + __int_as_float(sh);
}

// ---------------------------------------------------------------------------
// Monolithic scan v7 (unchanged): xc d-chunked; dt via in-kernel MFMA;
// t4 loop software-pipelined. Grid 512 x 256.
// ---------------------------------------------------------------------------
__global__ __launch_bounds__(256) void scan_fused(
    const float* __restrict__ xc, const float* __restrict__ xdbl,
    const unsigned short* __restrict__ dtwb,
    const float* __restrict__ dtpb,
    const float* __restrict__ A_log, const float* __restrict__ Dm,
    const unsigned short* __restrict__ xzb, unsigned short* __restrict__ ysb16)
{
    __shared__ float4 sdp [CL / 2][17];
    __shared__ float4 sbc4[CL / 2][17];
    __shared__ float  sy  [16][CL + 4];

    const int tid  = threadIdx.x;
    const int s    = tid & 15;
    const int grp  = tid >> 4;
    const int bd0  = blockIdx.x * 16;
    const int b    = bd0 >> 10;
    const int d0   = bd0 & (DI - 1);
    const int mb0  = b * L_;

    const int j    = tid & 15;
    const int tt   = tid >> 4;
    const int lane = tid & 63;
    const int w    = tid >> 6;
    const int q    = lane >> 4;
    const int tW   = 32 * w;

    const float a    = -__expf(A_log[(d0 + grp) * DS + s]);
    const float dmv  = Dm[d0 + j];
    const float bias = dtpb[d0 + j];

    const float* xcc = xc + (long)(d0 >> 4) * (BL * 16);
    const bf16x8 bfrag = *(const bf16x8*)(dtwb + (d0 + j) * 32 + q * 8);

    float  rB[8], rC[8];
    bf16x8 ra[2];
    float  rxc[2][4], rz[2][4];

#pragma unroll
    for (int i = 0; i < 8; ++i) {
        int m = mb0 + tt + 16 * i;
        rB[i] = xdbl[m * 64 + DTR + j];
        rC[i] = xdbl[m * 64 + DTR + DS + j];
    }
#pragma unroll
    for (int tile = 0; tile < 2; ++tile) {
        ra[tile] = ldcvt_bf8(xdbl + (long)(mb0 + tW + tile * 16 + j) * 64 + q * 8);
#pragma unroll
        for (int r = 0; r < 4; ++r) {
            int t = tW + tile * 16 + q * 4 + r;
            rxc[tile][r] = xcc[(long)(mb0 + t) * 16 + j];
            rz [tile][r] = bf2f(xzb[(long)(mb0 + t) * (2 * DI) + DI + d0 + j]);
        }
    }

    float state = 0.f;

    for (int c = 0; c < NCH; ++c) {
        const int mbase = mb0 + c * CL;
        float xcur[2][4], zcur[2][4];
#pragma unroll
        for (int tile = 0; tile < 2; ++tile)
#pragma unroll
            for (int r = 0; r < 4; ++r) {
                xcur[tile][r] = rxc[tile][r];
                zcur[tile][r] = rz[tile][r];
            }

        floatx4 dacc[2];
#pragma unroll
        for (int tile = 0; tile < 2; ++tile) {
            floatx4 cin;
            cin[0] = bias; cin[1] = bias; cin[2] = bias; cin[3] = bias;
            dacc[tile] = __builtin_amdgcn_mfma_f32_16x16x32_bf16(
                ra[tile], bfrag, cin, 0, 0, 0);
        }

        __syncthreads();
#pragma unroll
        for (int i = 0; i < 8; ++i) {
            int t = tt + 16 * i;
            ((float2*)&sbc4[t >> 1][j])[t & 1] = make_float2(rB[i], rC[i]);
        }
#pragma unroll
        for (int tile = 0; tile < 2; ++tile) {
#pragma unroll
            for (int r = 0; r < 4; ++r) {
                int t = tW + tile * 16 + q * 4 + r;
                float v = dacc[tile][r];
                float dt = (v > 20.f) ? v : __logf(1.f + __expf(v));
                ((float2*)&sdp[t >> 1][j])[t & 1] =
                    make_float2(dt * 1.44269504f, dt * xcur[tile][r]);
            }
        }
        __syncthreads();

        if (c < NCH - 1) {
            const int mn = mbase + CL;
#pragma unroll
            for (int i = 0; i < 8; ++i) {
                int m = mn + tt + 16 * i;
                rB[i] = xdbl[m * 64 + DTR + j];
                rC[i] = xdbl[m * 64 + DTR + DS + j];
            }
#pragma unroll
            for (int tile = 0; tile < 2; ++tile) {
                ra[tile] = ldcvt_bf8(xdbl + (long)(mn + tW + tile * 16 + j) * 64 + q * 8);
#pragma unroll
                for (int r = 0; r < 4; ++r) {
                    int t = tW + tile * 16 + q * 4 + r;
                    rxc[tile][r] = xcc[(long)(mn + t) * 16 + j];
                    rz [tile][r] = bf2f(xzb[(long)(mn + t) * (2 * DI) + DI + d0 + j]);
                }
            }
        }

        float4 dp0 = sdp[0][grp], bc0 = sbc4[0][s];
        float4 dp1 = sdp[1][grp], bc1 = sbc4[1][s];
        for (int t4 = 0; t4 < CL; t4 += 4) {
            const int t2n = (t4 >> 1) + 2;
            const int t2c = (t2n < CL / 2) ? t2n : 0;
            float4 dpn0 = sdp[t2c][grp];
            float4 bcn0 = sbc4[t2c][s];
            float4 dpn1 = sdp[t2c + 1][grp];
            float4 bcn1 = sbc4[t2c + 1][s];

            float ybuf[4];
            {
                const float dA = EXP2(dp0.x * a);
                state = fmaf(dA, state, dp0.y * bc0.x);
                float contrib = state * bc0.y;
                contrib = dpp_shr_add<0x111>(contrib);
                contrib = dpp_shr_add<0x112>(contrib);
                contrib = dpp_shr_add<0x114>(contrib);
                contrib = dpp_shr_add<0x118>(contrib);
                ybuf[0] = contrib;
            }
            {
                const float dA = EXP2(dp0.z * a);
                state = fmaf(dA, state, dp0.w * bc0.z);
                float contrib = state * bc0.w;
                contrib = dpp_shr_add<0x111>(contrib);
                contrib = dpp_shr_add<0x112>(contrib);
                contrib = dpp_shr_add<0x114>(contrib);
                contrib = dpp_shr_add<0x118>(contrib);
                ybuf[1] = contrib;
            }
            {
                const float dA = EXP2(dp1.x * a);
                state = fmaf(dA, state, dp1.y * bc1.x);
                float contrib = state * bc1.y;
                contrib = dpp_shr_add<0x111>(contrib);
                contrib = dpp_shr_add<0x112>(contrib);
                contrib = dpp_shr_add<0x114>(contrib);
                contrib = dpp_shr_add<0x118>(contrib);
                ybuf[2] = contrib;
            }
            {
                const float dA = EXP2(dp1.z * a);
                state = fmaf(dA, state, dp1.w * bc1.z);
                float contrib = state * bc1.w;
                contrib = dpp_shr_add<0x111>(contrib);
                contrib = dpp_shr_add<0x112>(contrib);
                contrib = dpp_shr_add<0x114>(contrib);
                contrib = dpp_shr_add<0x118>(contrib);
                ybuf[3] = contrib;
            }
            if (s == 15) *(float4*)&sy[grp][t4] = *(float4*)ybuf;
            dp0 = dpn0; bc0 = bcn0; dp1 = dpn1; bc1 = bcn1;
        }
        __syncthreads();

#pragma unroll
        for (int tile = 0; tile < 2; ++tile) {
#pragma unroll
            for (int r = 0; r < 4; ++r) {
                int t = tW + tile * 16 + q * 4 + r;
                float z = zcur[tile][r];
                float sz = z / (1.f + __expf(-z));
                float val = (sy[j][t] + xcur[tile][r] * dmv) * sz;
                ysb16[(long)(mbase + t) * DI + d0 + j] = f2bf(val);
            }
        }
    }
}

// ---------------------------------------------------------------------------
extern "C" void kernel_launch(void* const* d_in, const int* in_sizes, int n_in,
                              void* d_out, int out_size, void* d_ws, size_t ws_size,
                              hipStream_t stream) {
    const float* x          = (const float*)d_in[0];
    const float* proj_in_w  = (const float*)d_in[1];
    const float* proj_in_b  = (const float*)d_in[2];
    const float* in_proj_w  = (const float*)d_in[3];
    const float* conv_w     = (const float*)d_in[4];
    const float* conv_b     = (const float*)d_in[5];
    const float* x_proj_w   = (const float*)d_in[6];
    const float* dt_proj_w  = (const float*)d_in[7];
    const float* dt_proj_b  = (const float*)d_in[8];
    const float* A_log      = (const float*)d_in[9];
    const float* Dm         = (const float*)d_in[10];
    const float* out_proj_w = (const float*)d_in[11];
    const float* cls_w1     = (const float*)d_in[12];
    const float* cls_b1     = (const float*)d_in[13];
    const float* cls_w2     = (const float*)d_in[14];
    const float* cls_b2     = (const float*)d_in[15];
    float* out = (float*)d_out;

    float* ws   = (float*)d_ws;
    float* h    = ws;                       // layout keeper
    float* xzf  = h    + BL * DM;           // bf16 xz region
    float* xcb  = xzf  + BL * 2 * DI;
    float* xdbl = xcb  + BL * DI;
    float* scr  = xdbl + BL * 64;
    float* hm   = scr  + 2 * BL * DI;
    float* hmp  = hm   + B_ * DM;           // counters live here
    unsigned short* xzb  = (unsigned short*)xzf;
    unsigned short* u16  = (unsigned short*)(hmp + 64 * DM);
    unsigned short* xbf  = u16;
    unsigned short* hbf  = xbf  + BL * DIN;
    unsigned short* ysbf = hbf  + BL * DM;
    unsigned short* wpin = ysbf + BL * DI;
    unsigned short* win  = wpin + DM * DIN;
    unsigned short* wout = win  + NLAY * 2 * DI * DM;

    float* xpart = scr;                                        // KS*BL*64
    unsigned short* dtwb = (unsigned short*)(scr + 6 * 1024 * 1024 + 262144 + 131072 + 16384);
    int* cnt  = (int*)hmp;       // [0..63] xprojconv per-by; [64] out_proj
    int* cnt2 = cnt + 64;

    cvt_all<<<1858, 256, 0, stream>>>(x, xbf, proj_in_w, wpin,
                                      in_proj_w, win, out_proj_w, wout,
                                      dt_proj_w, dtwb, hm, cnt);

    gemm_mfma_n64<<<dim3(DM / 64, BL / 128), 256, 0, stream>>>(
        xbf, wpin, proj_in_b, nullptr, hbf, DM, DIN, 0, nullptr,
        nullptr, nullptr, nullptr, nullptr, nullptr, nullptr);

    for (int l = 0; l < NLAY; ++l) {
        gemm_mfma<<<dim3(2 * DI / 128, BL / 128), 256, 0, stream>>>(
            hbf, win + l * 2 * DI * DM, nullptr, xzb, 2 * DI, DM);
        xprojconv<<<dim3(KS, 64), 256, 0, stream>>>(
            xzb, conv_w + l * DI * 4, conv_b + l * DI,
            x_proj_w + l * 64 * DI, xpart, xcb, xdbl, cnt);
        scan_fused<<<(B_ * DI) / 16, 256, 0, stream>>>(
            xcb, xdbl, dtwb + l * DI * 32, dt_proj_b + l * DI,
            A_log + l * DI * DS, Dm + l * DI, xzb, ysbf);
        if (l == NLAY - 1) {
            gemm_mfma_n64<<<dim3(DM / 64, BL / 128), 256, 0, stream>>>(
                ysbf, wout + l * DM * DI, nullptr, nullptr, nullptr,
                DM, DI, 1, hm, cls_w1, cls_b1, cls_w2, cls_b2, out, cnt2);
        } else {
            gemm_mfma_n64<<<dim3(DM / 64, BL / 128), 256, 0, stream>>>(
                ysbf, wout + l * DM * DI, nullptr, nullptr, hbf,
                DM, DI, 0, nullptr,
                nullptr, nullptr, nullptr, nullptr, nullptr, nullptr);
        }
    }
}

// Round 11
// 307.151 us; speedup vs baseline: 1.3063x; 1.3063x over previous
//
#include <hip/hip_runtime.h>
#include <hip/hip_bf16.h>

// Dims (fixed by the reference)
#define B_   8
#define L_   512
#define DIN  128
#define DM   512
#define NLAY 2
#define DI   1024     // d_inner
#define DS   16       // d_state
#define DTR  32       // dt_rank
#define BL   (B_ * L_)   // 4096
#define KS   8           // x_proj split-K slices
#define CL   128         // scan chunk length (staged in LDS)
#define NCH  (L_ / CL)   // 4

typedef short bf16x8 __attribute__((ext_vector_type(8)));
typedef float floatx4 __attribute__((ext_vector_type(4)));

__device__ __forceinline__ unsigned short f2bf(float f) {
    unsigned int u = __float_as_uint(f);
    unsigned int r = (u + 0x7FFF + ((u >> 16) & 1)) >> 16;   // RNE
    return (unsigned short)r;
}
__device__ __forceinline__ float bf2f(unsigned short u) {
    return __uint_as_float((unsigned int)u << 16);
}

#if __has_builtin(__builtin_amdgcn_exp2f)
#define EXP2(x) __builtin_amdgcn_exp2f(x)
#else
#define EXP2(x) __expf((x) * 0.69314718056f)
#endif

// Async global->LDS, 16B per lane. LDS dest must be linear: wave-uniform base
// + lane*16 (m104/m108). Our chunk mapping satisfies this exactly.
__device__ __forceinline__ void gld_lds16(const unsigned short* g, unsigned short* l) {
    __builtin_amdgcn_global_load_lds(
        (const __attribute__((address_space(1))) void*)g,
        (__attribute__((address_space(3))) void*)l,
        16, 0, 0);
}

// Load 8 consecutive fp32 and pack to a bf16x8 fragment (RNE).
__device__ __forceinline__ bf16x8 ldcvt_bf8(const float* __restrict__ p) {
    float4 a = *(const float4*)p;
    float4 b = *(const float4*)(p + 4);
    unsigned short o[8];
    o[0] = f2bf(a.x); o[1] = f2bf(a.y); o[2] = f2bf(a.z); o[3] = f2bf(a.w);
    o[4] = f2bf(b.x); o[5] = f2bf(b.y); o[6] = f2bf(b.z); o[7] = f2bf(b.w);
    return *(bf16x8*)o;
}

// ---------------------------------------------------------------------------
// Fused fp32->bf16 conversion (x, proj_in_w, in_proj_w, out_proj_w, dt_proj_w
// stride-32 bf16) + zero hm.
// ---------------------------------------------------------------------------
__global__ __launch_bounds__(256) void cvt_all(
    const float* __restrict__ x,  unsigned short* __restrict__ xbf,
    const float* __restrict__ pw, unsigned short* __restrict__ wpin,
    const float* __restrict__ iw, unsigned short* __restrict__ win,
    const float* __restrict__ ow, unsigned short* __restrict__ wout,
    const float* __restrict__ dtp, unsigned short* __restrict__ dtwb,
    float* __restrict__ hm)
{
    int bid = blockIdx.x;
    if (bid >= 1856) {                       // zero hm (B_*DM = 4096 floats)
        int i = (bid - 1856) * 2048 + threadIdx.x * 8;
        float4 z = make_float4(0.f, 0.f, 0.f, 0.f);
        *(float4*)(hm + i) = z;
        *(float4*)(hm + i + 4) = z;
        return;
    }
    const float* src; unsigned short* dst; int off;
    if      (bid < 256)  { src = x;   dst = xbf;  off = bid; }
    else if (bid < 288)  { src = pw;  dst = wpin; off = bid - 256; }
    else if (bid < 1312) { src = iw;  dst = win;  off = bid - 288; }
    else if (bid < 1824) { src = ow;  dst = wout; off = bid - 1312; }
    else                 { src = dtp; dst = dtwb; off = bid - 1824; }  // 32 blocks
    int i = (off * 256 + threadIdx.x) * 8;
    float4 a = *(const float4*)(src + i);
    float4 b = *(const float4*)(src + i + 4);
    unsigned short o[8];
    o[0] = f2bf(a.x); o[1] = f2bf(a.y); o[2] = f2bf(a.z); o[3] = f2bf(a.w);
    o[4] = f2bf(b.x); o[5] = f2bf(b.y); o[6] = f2bf(b.z); o[7] = f2bf(b.w);
    *(uint4*)(dst + i) = *(uint4*)o;
}

// ---------------------------------------------------------------------------
// bf16 MFMA GEMM, tile 128x128, BK=64, m97 structure (single-buffered):
// global_load_lds width-16 staging into linear LDS, 2 barriers per K-step.
// ---------------------------------------------------------------------------
__global__ __launch_bounds__(256) void gemm_mfma(
    const unsigned short* __restrict__ A,
    const unsigned short* __restrict__ W,
    float* __restrict__ C, unsigned short* __restrict__ Cb,
    int N, int K)
{
    __shared__ unsigned short As[128 * 64];   // 16 KB, linear (row stride 64 shorts)
    __shared__ unsigned short Ws[128 * 64];   // 16 KB

    const int tid  = threadIdx.x;
    const int lane = tid & 63;
    const int wv   = tid >> 6;
    const int wm   = (wv >> 1) * 64;
    const int wn   = (wv & 1) * 64;
    const int lr   = lane & 15;
    const int q    = lane >> 4;

    // staging: 1KB chunk = 8 rows x 64 shorts; lane l -> byte l*16 of chunk.
    const int srow  = lane >> 3;          // row within chunk (0..7)
    const int skcol = (lane & 7) * 8;     // short col within row
    const long aRowBase = (long)blockIdx.y * 128;
    const long wRowBase = (long)blockIdx.x * 128;

    floatx4 acc[4][4];
#pragma unroll
    for (int i = 0; i < 4; ++i)
#pragma unroll
        for (int j = 0; j < 4; ++j)
#pragma unroll
            for (int r = 0; r < 4; ++r) acc[i][j][r] = 0.f;

    for (int k0 = 0; k0 < K; k0 += 64) {
        __syncthreads();   // previous compute done reading LDS
#pragma unroll
        for (int c = 0; c < 4; ++c) {
            const int chunk = wv * 4 + c;
            const int row   = chunk * 8 + srow;
            gld_lds16(A + (aRowBase + row) * K + k0 + skcol,
                      As + chunk * 512 + lane * 8);
            gld_lds16(W + (wRowBase + row) * K + k0 + skcol,
                      Ws + chunk * 512 + lane * 8);
        }
        __syncthreads();   // vmcnt(0) drained before barrier -> tiles ready

#pragma unroll
        for (int kk = 0; kk < 2; ++kk) {
            bf16x8 af[4], bfr[4];
#pragma unroll
            for (int i = 0; i < 4; ++i)
                af[i] = *(const bf16x8*)(As + (wm + i * 16 + lr) * 64 + kk * 32 + q * 8);
#pragma unroll
            for (int j = 0; j < 4; ++j)
                bfr[j] = *(const bf16x8*)(Ws + (wn + j * 16 + lr) * 64 + kk * 32 + q * 8);
#pragma unroll
            for (int i = 0; i < 4; ++i)
#pragma unroll
                for (int j = 0; j < 4; ++j)
                    acc[i][j] = __builtin_amdgcn_mfma_f32_16x16x32_bf16(
                        af[i], bfr[j], acc[i][j], 0, 0, 0);
        }
    }

#pragma unroll
    for (int i = 0; i < 4; ++i) {
#pragma unroll
        for (int r = 0; r < 4; ++r) {
            const int  crow = blockIdx.y * 128 + wm + i * 16 + q * 4 + r;
            const long base = (long)crow * N + blockIdx.x * 128 + wn + lr;
#pragma unroll
            for (int j = 0; j < 4; ++j) {
                float v = acc[i][j][r];
                if (C)  C[base + j * 16] = v;
                if (Cb) Cb[base + j * 16] = f2bf(v);
            }
        }
    }
}

// ---------------------------------------------------------------------------
// bf16 MFMA GEMM, tile 128(M)x64(N), BK=64, m97-style staging (single-buffer).
// meanmode: accumulate column sums / L into hm instead of writing C/Cb.
// ---------------------------------------------------------------------------
__global__ __launch_bounds__(256) void gemm_mfma_n64(
    const unsigned short* __restrict__ A,
    const unsigned short* __restrict__ W,
    const float* __restrict__ bias,
    float* __restrict__ C, unsigned short* __restrict__ Cb,
    int N, int K, int meanmode, float* __restrict__ hm)
{
    __shared__ unsigned short As[128 * 64];   // 16 KB
    __shared__ unsigned short Ws[64 * 64];    // 8 KB
    __shared__ float colsum[64];

    const int tid  = threadIdx.x;
    const int lane = tid & 63;
    const int wv   = tid >> 6;
    const int wm   = wv * 32;
    const int lr   = lane & 15;
    const int q    = lane >> 4;

    const int srow  = lane >> 3;
    const int skcol = (lane & 7) * 8;
    const long aRowBase = (long)blockIdx.y * 128;
    const long wRowBase = (long)blockIdx.x * 64;

    floatx4 acc[2][4];
#pragma unroll
    for (int i = 0; i < 2; ++i)
#pragma unroll
        for (int j = 0; j < 4; ++j)
#pragma unroll
            for (int r = 0; r < 4; ++r) acc[i][j][r] = 0.f;

    for (int k0 = 0; k0 < K; k0 += 64) {
        __syncthreads();
#pragma unroll
        for (int c = 0; c < 4; ++c) {          // A: 16 chunks, 4 per wave
            const int chunk = wv * 4 + c;
            const int row   = chunk * 8 + srow;
            gld_lds16(A + (aRowBase + row) * K + k0 + skcol,
                      As + chunk * 512 + lane * 8);
        }
#pragma unroll
        for (int c = 0; c < 2; ++c) {          // W: 8 chunks, 2 per wave
            const int chunk = wv * 2 + c;
            const int row   = chunk * 8 + srow;
            gld_lds16(W + (wRowBase + row) * K + k0 + skcol,
                      Ws + chunk * 512 + lane * 8);
        }
        __syncthreads();

#pragma unroll
        for (int kk = 0; kk < 2; ++kk) {
            bf16x8 af[2], bfr[4];
#pragma unroll
            for (int i = 0; i < 2; ++i)
                af[i] = *(const bf16x8*)(As + (wm + i * 16 + lr) * 64 + kk * 32 + q * 8);
#pragma unroll
            for (int j = 0; j < 4; ++j)
                bfr[j] = *(const bf16x8*)(Ws + (j * 16 + lr) * 64 + kk * 32 + q * 8);
#pragma unroll
            for (int i = 0; i < 2; ++i)
#pragma unroll
                for (int j = 0; j < 4; ++j)
                    acc[i][j] = __builtin_amdgcn_mfma_f32_16x16x32_bf16(
                        af[i], bfr[j], acc[i][j], 0, 0, 0);
        }
    }

    if (meanmode) {
        if (tid < 64) colsum[tid] = 0.f;
        __syncthreads();
#pragma unroll
        for (int j = 0; j < 4; ++j) {
            float p = 0.f;
#pragma unroll
            for (int i = 0; i < 2; ++i)
#pragma unroll
                for (int r = 0; r < 4; ++r) p += acc[i][j][r];
            atomicAdd(&colsum[j * 16 + lr], p);
        }
        __syncthreads();
        if (tid < 64) {
            const int b = blockIdx.y >> 2;   // 4 row-blocks per batch
            atomicAdd(&hm[b * DM + blockIdx.x * 64 + tid],
                      colsum[tid] * (1.f / (float)L_));
        }
        return;
    }

    float bj[4] = {0.f, 0.f, 0.f, 0.f};
    if (bias) {
#pragma unroll
        for (int j = 0; j < 4; ++j)
            bj[j] = bias[blockIdx.x * 64 + j * 16 + lr];
    }
#pragma unroll
    for (int i = 0; i < 2; ++i) {
#pragma unroll
        for (int r = 0; r < 4; ++r) {
            const int  crow = blockIdx.y * 128 + wm + i * 16 + q * 4 + r;
            const long base = (long)crow * N + blockIdx.x * 64 + lr;
#pragma unroll
            for (int j = 0; j < 4; ++j) {
                float v = acc[i][j][r] + bj[j];
                if (C)  C[base + j * 16] = v;
                if (Cb) Cb[base + j * 16] = f2bf(v);
            }
        }
    }
}

// ---------------------------------------------------------------------------
// Fused causal-conv(k=4)+silu + x_proj split-K stage 1 (partials to P).
// xcout written in d-chunked layout [DI/16][BL][16] (fp32, bit-exact).
// ---------------------------------------------------------------------------
__global__ __launch_bounds__(256) void xprojconv(
    const unsigned short* __restrict__ xzb, const float* __restrict__ cw,
    const float* __restrict__ cb, const float* __restrict__ W,
    float* __restrict__ P, float* __restrict__ xcout)
{
    __shared__ float As[16][68];
    __shared__ float Ws[16][68];

    const int tid  = threadIdx.x;
    const int tx   = tid & 15;
    const int ty   = tid >> 4;
    const int lrow = tid >> 2;
    const int lk   = (tid & 3) << 2;
    const int kbase = blockIdx.x * (DI / KS);

    const int m = blockIdx.y * 64 + lrow;
    const int t = m & (L_ - 1);
    const float* Wp = W + lrow * DI + kbase + lk;

    float acc[4][4] = {};

    for (int k0 = 0; k0 < DI / KS; k0 += 16) {
        const int dcol = kbase + k0 + lk;
        float4 cbv = *(const float4*)(cb + dcol);
        float sums[4] = {cbv.x, cbv.y, cbv.z, cbv.w};
        float4 cwq[4];
#pragma unroll
        for (int q = 0; q < 4; ++q) cwq[q] = *(const float4*)(cw + (dcol + q) * 4);
#pragma unroll
        for (int w = 0; w < 4; ++w) {
            int tw = t - 3 + w;
            if (tw >= 0) {
                const uint2 up = *(const uint2*)(xzb + (long)(m - 3 + w) * (2 * DI) + dcol);
                float x0 = __uint_as_float(up.x << 16);
                float x1 = __uint_as_float(up.x & 0xffff0000u);
                float x2 = __uint_as_float(up.y << 16);
                float x3 = __uint_as_float(up.y & 0xffff0000u);
                sums[0] += ((const float*)&cwq[0])[w] * x0;
                sums[1] += ((const float*)&cwq[1])[w] * x1;
                sums[2] += ((const float*)&cwq[2])[w] * x2;
                sums[3] += ((const float*)&cwq[3])[w] * x3;
            }
        }
        float4 a4;
#pragma unroll
        for (int q = 0; q < 4; ++q)
            ((float*)&a4)[q] = sums[q] / (1.f + __expf(-sums[q]));
        float4 wv = *(const float4*)(Wp + k0);
        // d-chunked store: chunk = dcol>>4, offset lk = dcol&15
        *(float4*)(xcout + (long)(dcol >> 4) * (BL * 16) + (long)m * 16 + lk) = a4;

        __syncthreads();
        As[lk + 0][lrow] = a4.x; As[lk + 1][lrow] = a4.y;
        As[lk + 2][lrow] = a4.z; As[lk + 3][lrow] = a4.w;
        Ws[lk + 0][lrow] = wv.x; Ws[lk + 1][lrow] = wv.y;
        Ws[lk + 2][lrow] = wv.z; Ws[lk + 3][lrow] = wv.w;
        __syncthreads();
#pragma unroll
        for (int k = 0; k < 16; ++k) {
            const float4 a44 = *(const float4*)&As[k][ty << 2];
            const float4 w4  = *(const float4*)&Ws[k][tx << 2];
            acc[0][0] += a44.x * w4.x; acc[0][1] += a44.x * w4.y;
            acc[0][2] += a44.x * w4.z; acc[0][3] += a44.x * w4.w;
            acc[1][0] += a44.y * w4.x; acc[1][1] += a44.y * w4.y;
            acc[1][2] += a44.y * w4.z; acc[1][3] += a44.y * w4.w;
            acc[2][0] += a44.z * w4.x; acc[2][1] += a44.z * w4.y;
            acc[2][2] += a44.z * w4.z; acc[2][3] += a44.z * w4.w;
            acc[3][0] += a44.w * w4.x; acc[3][1] += a44.w * w4.y;
            acc[3][2] += a44.w * w4.z; acc[3][3] += a44.w * w4.w;
        }
    }

    float* out = P + (long)blockIdx.x * (BL * 64)
               + (blockIdx.y * 64 + (ty << 2)) * 64 + (tx << 2);
#pragma unroll
    for (int i = 0; i < 4; ++i)
        *(float4*)(out + i * 64) = make_float4(acc[i][0], acc[i][1],
                                               acc[i][2], acc[i][3]);
}

// Reduce split-K partials -> xdbl (fp32 only; scan converts on the fly).
__global__ __launch_bounds__(256) void xproj_reduce(
    const float* __restrict__ P, float* __restrict__ xdbl)
{
    int i = (blockIdx.x * 256 + threadIdx.x) * 4;
    float4 s = *(const float4*)(P + i);
#pragma unroll
    for (int k = 1; k < KS; ++k) {
        float4 p = *(const float4*)(P + (long)k * (BL * 64) + i);
        s.x += p.x; s.y += p.y; s.z += p.z; s.w += p.w;
    }
    *(float4*)(xdbl + i) = s;
}

// ---------------------------------------------------------------------------
template <int CTRL>
__device__ __forceinline__ float dpp_shr_add(float v) {
    int sh = __builtin_amdgcn_update_dpp(0, __float_as_int(v), CTRL, 0xF, 0xF, true);
    return v + __int_as_float(sh);
}

// ---------------------------------------------------------------------------
// Monolithic scan v8: v7 + s_setprio(1) around the serial t4 recurrence
// (T5: blocks on a CU are at different phases; boost the wave doing the
// latency-critical serial chain over co-resident blocks' staging).
// Grid 512 x 256.
// ---------------------------------------------------------------------------
__global__ __launch_bounds__(256) void scan_fused(
    const float* __restrict__ xc, const float* __restrict__ xdbl,
    const unsigned short* __restrict__ dtwb,
    const float* __restrict__ dtpb,
    const float* __restrict__ A_log, const float* __restrict__ Dm,
    const unsigned short* __restrict__ xzb, unsigned short* __restrict__ ysb16)
{
    __shared__ float4 sdp [CL / 2][17];
    __shared__ float4 sbc4[CL / 2][17];
    __shared__ float  sy  [16][CL + 4];

    const int tid  = threadIdx.x;
    const int s    = tid & 15;
    const int grp  = tid >> 4;
    const int bd0  = blockIdx.x * 16;
    const int b    = bd0 >> 10;
    const int d0   = bd0 & (DI - 1);
    const int mb0  = b * L_;

    const int j    = tid & 15;        // == lane&15; d-index for loads/epilogue
    const int tt   = tid >> 4;
    const int lane = tid & 63;
    const int w    = tid >> 6;
    const int q    = lane >> 4;
    const int tW   = 32 * w;          // wave's time base within a chunk

    const float a    = -__expf(A_log[(d0 + grp) * DS + s]);
    const float dmv  = Dm[d0 + j];
    const float bias = dtpb[d0 + j];

    // d-chunked xc panel for this block: [BL][16] slice of chunk d0>>4
    const float* xcc = xc + (long)(d0 >> 4) * (BL * 16);

    // constant B-fragment: dtw row d0+j, k-slice q*8 (K=32)
    const bf16x8 bfrag = *(const bf16x8*)(dtwb + (d0 + j) * 32 + q * 8);

    float  rB[8], rC[8];
    bf16x8 ra[2];
    float  rxc[2][4], rz[2][4];

    // prefetch chunk 0
#pragma unroll
    for (int i = 0; i < 8; ++i) {
        int m = mb0 + tt + 16 * i;
        rB[i] = xdbl[m * 64 + DTR + j];
        rC[i] = xdbl[m * 64 + DTR + DS + j];
    }
#pragma unroll
    for (int tile = 0; tile < 2; ++tile) {
        ra[tile] = ldcvt_bf8(xdbl + (long)(mb0 + tW + tile * 16 + j) * 64 + q * 8);
#pragma unroll
        for (int r = 0; r < 4; ++r) {
            int t = tW + tile * 16 + q * 4 + r;
            rxc[tile][r] = xcc[(long)(mb0 + t) * 16 + j];
            rz [tile][r] = bf2f(xzb[(long)(mb0 + t) * (2 * DI) + DI + d0 + j]);
        }
    }

    float state = 0.f;

    for (int c = 0; c < NCH; ++c) {
        const int mbase = mb0 + c * CL;
        float xcur[2][4], zcur[2][4];
#pragma unroll
        for (int tile = 0; tile < 2; ++tile)
#pragma unroll
            for (int r = 0; r < 4; ++r) {
                xcur[tile][r] = rxc[tile][r];
                zcur[tile][r] = rz[tile][r];
            }

        // dt via MFMA: D[t = tW + tile*16 + q*4 + r][d = d0 + j]
        floatx4 dacc[2];
#pragma unroll
        for (int tile = 0; tile < 2; ++tile) {
            floatx4 cin;
            cin[0] = bias; cin[1] = bias; cin[2] = bias; cin[3] = bias;
            dacc[tile] = __builtin_amdgcn_mfma_f32_16x16x32_bf16(
                ra[tile], bfrag, cin, 0, 0, 0);
        }

        __syncthreads();
#pragma unroll
        for (int i = 0; i < 8; ++i) {
            int t = tt + 16 * i;
            ((float2*)&sbc4[t >> 1][j])[t & 1] = make_float2(rB[i], rC[i]);
        }
#pragma unroll
        for (int tile = 0; tile < 2; ++tile) {
#pragma unroll
            for (int r = 0; r < 4; ++r) {
                int t = tW + tile * 16 + q * 4 + r;
                float v = dacc[tile][r];
                float dt = (v > 20.f) ? v : __logf(1.f + __expf(v));
                ((float2*)&sdp[t >> 1][j])[t & 1] =
                    make_float2(dt * 1.44269504f, dt * xcur[tile][r]);
            }
        }
        __syncthreads();

        if (c < NCH - 1) {
            const int mn = mbase + CL;
#pragma unroll
            for (int i = 0; i < 8; ++i) {
                int m = mn + tt + 16 * i;
                rB[i] = xdbl[m * 64 + DTR + j];
                rC[i] = xdbl[m * 64 + DTR + DS + j];
            }
#pragma unroll
            for (int tile = 0; tile < 2; ++tile) {
                ra[tile] = ldcvt_bf8(xdbl + (long)(mn + tW + tile * 16 + j) * 64 + q * 8);
#pragma unroll
                for (int r = 0; r < 4; ++r) {
                    int t = tW + tile * 16 + q * 4 + r;
                    rxc[tile][r] = xcc[(long)(mn + t) * 16 + j];
                    rz [tile][r] = bf2f(xzb[(long)(mn + t) * (2 * DI) + DI + d0 + j]);
                }
            }
        }

        // --- software-pipelined scan loop (setprio-boosted serial chain) ---
        __builtin_amdgcn_s_setprio(1);
        float4 dp0 = sdp[0][grp], bc0 = sbc4[0][s];
        float4 dp1 = sdp[1][grp], bc1 = sbc4[1][s];
        for (int t4 = 0; t4 < CL; t4 += 4) {
            const int t2n = (t4 >> 1) + 2;
            const int t2c = (t2n < CL / 2) ? t2n : 0;   // clamp (last iter discards)
            float4 dpn0 = sdp[t2c][grp];
            float4 bcn0 = sbc4[t2c][s];
            float4 dpn1 = sdp[t2c + 1][grp];
            float4 bcn1 = sbc4[t2c + 1][s];

            float ybuf[4];
            {
                const float dA = EXP2(dp0.x * a);
                state = fmaf(dA, state, dp0.y * bc0.x);
                float contrib = state * bc0.y;
                contrib = dpp_shr_add<0x111>(contrib);
                contrib = dpp_shr_add<0x112>(contrib);
                contrib = dpp_shr_add<0x114>(contrib);
                contrib = dpp_shr_add<0x118>(contrib);
                ybuf[0] = contrib;
            }
            {
                const float dA = EXP2(dp0.z * a);
                state = fmaf(dA, state, dp0.w * bc0.z);
                float contrib = state * bc0.w;
                contrib = dpp_shr_add<0x111>(contrib);
                contrib = dpp_shr_add<0x112>(contrib);
                contrib = dpp_shr_add<0x114>(contrib);
                contrib = dpp_shr_add<0x118>(contrib);
                ybuf[1] = contrib;
            }
            {
                const float dA = EXP2(dp1.x * a);
                state = fmaf(dA, state, dp1.y * bc1.x);
                float contrib = state * bc1.y;
                contrib = dpp_shr_add<0x111>(contrib);
                contrib = dpp_shr_add<0x112>(contrib);
                contrib = dpp_shr_add<0x114>(contrib);
                contrib = dpp_shr_add<0x118>(contrib);
                ybuf[2] = contrib;
            }
            {
                const float dA = EXP2(dp1.z * a);
                state = fmaf(dA, state, dp1.w * bc1.z);
                float contrib = state * bc1.w;
                contrib = dpp_shr_add<0x111>(contrib);
                contrib = dpp_shr_add<0x112>(contrib);
                contrib = dpp_shr_add<0x114>(contrib);
                contrib = dpp_shr_add<0x118>(contrib);
                ybuf[3] = contrib;
            }
            if (s == 15) *(float4*)&sy[grp][t4] = *(float4*)ybuf;
            dp0 = dpn0; bc0 = bcn0; dp1 = dpn1; bc1 = bcn1;
        }
        __builtin_amdgcn_s_setprio(0);
        __syncthreads();

#pragma unroll
        for (int tile = 0; tile < 2; ++tile) {
#pragma unroll
            for (int r = 0; r < 4; ++r) {
                int t = tW + tile * 16 + q * 4 + r;
                float z = zcur[tile][r];
                float sz = z / (1.f + __expf(-z));
                float val = (sy[j][t] + xcur[tile][r] * dmv) * sz;
                ysb16[(long)(mbase + t) * DI + d0 + j] = f2bf(val);
            }
        }
    }
}

// ---------------------------------------------------------------------------
// Classifier head reading pre-accumulated mean hm. 8 blocks x 512 thr.
// ---------------------------------------------------------------------------
__global__ __launch_bounds__(512) void meancls_kernel(
    const float* __restrict__ hm, const float* __restrict__ w1,
    const float* __restrict__ b1, const float* __restrict__ w2,
    const float* __restrict__ b2, float* __restrict__ out)
{
    __shared__ float shm[DM];
    __shared__ float su[64];
    const int b = blockIdx.x, tid = threadIdx.x;
    shm[tid] = hm[b * DM + tid];
    __syncthreads();

    const int j = tid >> 3, sl = tid & 7;
    const float* wr = w1 + j * DM + sl * 64;
    const float* hb = shm + sl * 64;
    float p = 0.f;
    for (int k = 0; k < 64; k += 4)
        p += hb[k] * wr[k] + hb[k+1] * wr[k+1]
           + hb[k+2] * wr[k+2] + hb[k+3] * wr[k+3];
    p += __shfl_xor(p, 1);
    p += __shfl_xor(p, 2);
    p += __shfl_xor(p, 4);
    if (sl == 0) su[j] = fmaxf(p + b1[j], 0.f) * w2[j];
    __syncthreads();
    if (tid < 64) {
        float v = su[tid];
#pragma unroll
        for (int off = 32; off; off >>= 1) v += __shfl_down(v, off);
        if (tid == 0) out[b] = v + b2[0];
    }
}

// ---------------------------------------------------------------------------
extern "C" void kernel_launch(void* const* d_in, const int* in_sizes, int n_in,
                              void* d_out, int out_size, void* d_ws, size_t ws_size,
                              hipStream_t stream) {
    const float* x          = (const float*)d_in[0];
    const float* proj_in_w  = (const float*)d_in[1];
    const float* proj_in_b  = (const float*)d_in[2];
    const float* in_proj_w  = (const float*)d_in[3];
    const float* conv_w     = (const float*)d_in[4];
    const float* conv_b     = (const float*)d_in[5];
    const float* x_proj_w   = (const float*)d_in[6];
    const float* dt_proj_w  = (const float*)d_in[7];
    const float* dt_proj_b  = (const float*)d_in[8];
    const float* A_log      = (const float*)d_in[9];
    const float* Dm         = (const float*)d_in[10];
    const float* out_proj_w = (const float*)d_in[11];
    const float* cls_w1     = (const float*)d_in[12];
    const float* cls_b1     = (const float*)d_in[13];
    const float* cls_w2     = (const float*)d_in[14];
    const float* cls_b2     = (const float*)d_in[15];
    float* out = (float*)d_out;

    float* ws   = (float*)d_ws;
    float* h    = ws;                       // layout keeper
    float* xzf  = h    + BL * DM;           // bf16 xz region
    float* xcb  = xzf  + BL * 2 * DI;
    float* xdbl = xcb  + BL * DI;
    float* scr  = xdbl + BL * 64;
    float* hm   = scr  + 2 * BL * DI;
    float* hmp  = hm   + B_ * DM;           // layout keeper
    unsigned short* xzb  = (unsigned short*)xzf;
    unsigned short* u16  = (unsigned short*)(hmp + 64 * DM);
    unsigned short* xbf  = u16;
    unsigned short* hbf  = xbf  + BL * DIN;
    unsigned short* ysbf = hbf  + BL * DM;
    unsigned short* wpin = ysbf + BL * DI;
    unsigned short* win  = wpin + DM * DIN;
    unsigned short* wout = win  + NLAY * 2 * DI * DM;

    float* xpart = scr;                                        // KS*BL*64 = 2.10M f
    unsigned short* dtwb = (unsigned short*)(scr + 6 * 1024 * 1024 + 262144 + 131072 + 16384); // NLAY*DI*32 sh

    cvt_all<<<1858, 256, 0, stream>>>(x, xbf, proj_in_w, wpin,
                                      in_proj_w, win, out_proj_w, wout,
                                      dt_proj_w, dtwb, hm);

    gemm_mfma_n64<<<dim3(DM / 64, BL / 128), 256, 0, stream>>>(
        xbf, wpin, proj_in_b, nullptr, hbf, DM, DIN, 0, nullptr);

    for (int l = 0; l < NLAY; ++l) {
        gemm_mfma<<<dim3(2 * DI / 128, BL / 128), 256, 0, stream>>>(
            hbf, win + l * 2 * DI * DM, nullptr, xzb, 2 * DI, DM);
        xprojconv<<<dim3(KS, 64), 256, 0, stream>>>(
            xzb, conv_w + l * DI * 4, conv_b + l * DI,
            x_proj_w + l * 64 * DI, xpart, xcb);
        xproj_reduce<<<256, 256, 0, stream>>>(xpart, xdbl);
        scan_fused<<<(B_ * DI) / 16, 256, 0, stream>>>(
            xcb, xdbl, dtwb + l * DI * 32, dt_proj_b + l * DI,
            A_log + l * DI * DS, Dm + l * DI, xzb, ysbf);
        if (l == NLAY - 1) {
            gemm_mfma_n64<<<dim3(DM / 64, BL / 128), 256, 0, stream>>>(
                ysbf, wout + l * DM * DI, nullptr, nullptr, nullptr,
                DM, DI, 1, hm);
        } else {
            gemm_mfma_n64<<<dim3(DM / 64, BL / 128), 256, 0, stream>>>(
                ysbf, wout + l * DM * DI, nullptr, nullptr, hbf,
                DM, DI, 0, nullptr);
        }
    }

    meancls_kernel<<<B_, 512, 0, stream>>>(hm, cls_w1, cls_b1,
                                           cls_w2, cls_b2, out);
}